// Round 4
// baseline (3085.260 us; speedup 1.0000x reference)
//
#include <hip/hip_runtime.h>

// DownSample — sparse scatter-form MFMA implicit GEMM.
//
// Per-tap compacted pair lists (i=out row, j=in row), padded to 64-pair tiles.
// Wave = one tile: gather 64 A rows (all valid), MFMA vs wave-uniform W[k],
// scatter-add C via native atomics (pk_add_bf16 for conv1 -> h bf16,
// add_f32 for conv2 -> down). bn+relu as separate sweeps. Pool = round-3
// dense gather MFMA (8 taps, 50% valid — fine).
//
// MFMA 16x16x32 bf16 layouts (verified rounds 3):
//   A[m=lane&15][k=(lane>>4)*8+j]   B[k=(lane>>4)*8+j][n=lane&15]
//   C/D: n=lane&15, m=(lane>>4)*4+reg

#define NV 400000
#define ND 100000
#define CAP 2400000            // pair capacity (expected ~1.79M; >30 sigma)
#define CAP_TILES (CAP / 64)   // 37500

typedef __attribute__((ext_vector_type(8))) short  bf16x8;
typedef __attribute__((ext_vector_type(4))) float  f32x4;

__device__ __forceinline__ unsigned short f2b(float f) {
    unsigned int u = __builtin_bit_cast(unsigned int, f);
    u += 0x7fffu + ((u >> 16) & 1u);
    return (unsigned short)(u >> 16);
}
__device__ __forceinline__ float b2f(unsigned short u) {
    unsigned int v = (unsigned int)u << 16;
    return __builtin_bit_cast(float, v);
}
__device__ __forceinline__ void atomic_pk_bf16(unsigned short* p, unsigned int d) {
    asm volatile("global_atomic_pk_add_bf16 %0, %1, off" :: "v"(p), "v"(d) : "memory");
}

// ---- x fp32 -> bf16 -------------------------------------------------------
__global__ __launch_bounds__(256) void cvt_bf16_k(
    const float* __restrict__ in, unsigned short* __restrict__ out, int n)
{
    int t = (blockIdx.x * 256 + threadIdx.x) * 4;
    if (t >= n) return;
    float4 f = *(const float4*)(in + t);
    ushort4 u;
    u.x = f2b(f.x); u.y = f2b(f.y); u.z = f2b(f.z); u.w = f2b(f.w);
    *(ushort4*)(out + t) = u;
}

// ---- pack W[nk][ci][64] -> per-lane B fragments ---------------------------
__global__ __launch_bounds__(256) void pack_w_k(
    const float* __restrict__ W, unsigned short* __restrict__ out, int nk, int ci)
{
    int t = blockIdx.x * 256 + threadIdx.x;
    int steps = ci >> 5;
    if (t >= nk * steps * 4 * 64) return;
    int lane = t & 63;
    int nt   = (t >> 6) & 3;
    int rest = t >> 8;
    int s    = rest % steps;
    int k    = rest / steps;
    int col = lane & 15, quad = lane >> 4;
    int co = nt * 16 + col;
    bf16x8 frag;
#pragma unroll
    for (int j = 0; j < 8; ++j) {
        int cidx = s * 32 + quad * 8 + j;
        frag[j] = (short)f2b(W[((size_t)k * ci + cidx) * 64 + co]);
    }
    *(bf16x8*)(out + (size_t)t * 8) = frag;
}

// ---- pool map inversion + small-buffer zeroing ----------------------------
__global__ __launch_bounds__(256) void ck_init_k(
    int* __restrict__ ck, int* __restrict__ cnt,
    unsigned short* __restrict__ xrow, float* __restrict__ zrow)
{
    int t = blockIdx.x * 256 + threadIdx.x;
    if (t < ND * 8) ck[t] = NV;
    if (t < 27) cnt[t] = 0;
    if (t < 32) { ((ulonglong2*)xrow)[t] = ulonglong2{0, 0}; }  // x_bf row NV (64 bf16)
    if (t < 64) zrow[t] = 0.f;
}
__global__ __launch_bounds__(256) void ck_scatter_k(
    const int* __restrict__ kp_in, const int* __restrict__ kp_out,
    int* __restrict__ ck)
{
    int t = blockIdx.x * 256 + threadIdx.x;
    if (t >= 8 * NV) return;
    int j = kp_in[t];
    if (j == NV) return;
    int k = t / NV;
    ck[kp_out[t] * 8 + k] = j;
}

// ---- pair-list build: count / scan / fill ---------------------------------
__global__ __launch_bounds__(256) void pair_count_k(
    const int* __restrict__ km, int* __restrict__ cnt)
{
    const int lane = threadIdx.x & 63;
    const int k = blockIdx.y;
    const int* __restrict__ kmr = km + (size_t)k * NV;
    int base = blockIdx.x * 2048 + threadIdx.x;
    int local = 0;
#pragma unroll
    for (int u = 0; u < 8; ++u) {
        int i = base + u * 256;
        bool valid = (i < NV) && (kmr[i < NV ? i : 0] != NV);
        unsigned long long m = __ballot(valid);
        local += __popcll(m);
    }
    if (lane == 0) atomicAdd(&cnt[k], local);
}

__global__ __launch_bounds__(64) void pair_scan_k(
    const int* __restrict__ cnt, int* __restrict__ cnt2,
    int* __restrict__ tkm, int* __restrict__ ntl,
    int* __restrict__ pj, int* __restrict__ pi)
{
    __shared__ int soff[28];
    const int tid = threadIdx.x;
    if (tid == 0) {
        int o = 0;
        for (int k = 0; k < 27; ++k) { soff[k] = o; o += (cnt[k] + 63) & ~63; }
        soff[27] = (o >> 6) > CAP_TILES ? (CAP_TILES << 6) : o;
    }
    __syncthreads();
    const int ntiles = soff[27] >> 6;
    if (tid < 27) cnt2[tid] = soff[tid];
    if (tid == 27) ntl[0] = ntiles;
    // per-tile tap id
    for (int t = tid; t < ntiles; t += 64) {
        int p = t << 6, k = 26;
        for (int q = 0; q < 26; ++q) if (p < soff[q + 1]) { k = q; break; }
        tkm[t] = k;
    }
    // pad entries: j -> zero row, i -> dump row
    for (int idx = tid; idx < 27 * 64; idx += 64) {
        int k = idx >> 6, s = idx & 63;
        int slot = soff[k] + cnt[k] + s;
        int end  = soff[k] + ((cnt[k] + 63) & ~63);
        if (slot < end && slot < CAP) { pj[slot] = NV; pi[slot] = NV; }
    }
}

__global__ __launch_bounds__(256) void pair_fill_k(
    const int* __restrict__ km, int* __restrict__ cnt2,
    int* __restrict__ pj, int* __restrict__ pi)
{
    const int lane = threadIdx.x & 63;
    const int k = blockIdx.y;
    const int* __restrict__ kmr = km + (size_t)k * NV;
    int base = blockIdx.x * 2048 + threadIdx.x;
#pragma unroll
    for (int u = 0; u < 8; ++u) {
        int i = base + u * 256;
        int j = (i < NV) ? kmr[i] : NV;
        bool valid = (i < NV) && (j != NV);
        unsigned long long m = __ballot(valid);
        int nb = __popcll(m);
        int slot0 = 0;
        if (lane == 0 && nb) slot0 = atomicAdd(&cnt2[k], nb);
        slot0 = __shfl(slot0, 0);
        if (valid) {
            int rank = __popcll(m & ((1ull << lane) - 1ull));
            int s = slot0 + rank;
            if (s < CAP) { pj[s] = j; pi[s] = i; }
        }
    }
}

// ---- sparse conv: wave = 64-pair tile, K=CI, scatter-atomic output --------
template <int CI, bool OUT_BF16>
__global__ __launch_bounds__(256) void conv_sp(
    const unsigned short* __restrict__ xin,   // [(NV+1)][CI] bf16
    const unsigned short* __restrict__ Wp,    // packed frags
    const int* __restrict__ pj, const int* __restrict__ pi,
    const int* __restrict__ tkm, const int* __restrict__ ntl,
    float* __restrict__ outf, unsigned short* __restrict__ outh)
{
    constexpr int STEPS = CI / 32;
    const int lane = threadIdx.x & 63;
    const int wave = threadIdx.x >> 6;
    const int col = lane & 15, quad = lane >> 4;

    const int tile = blockIdx.x * 4 + wave;
    if (tile >= ntl[0]) return;
    const int k = __builtin_amdgcn_readfirstlane(tkm[tile]);
    const int base = tile << 6;

    int j[4];
#pragma unroll
    for (int mt = 0; mt < 4; ++mt) j[mt] = pj[base + mt * 16 + col];

    f32x4 acc[4][4];
#pragma unroll
    for (int mt = 0; mt < 4; ++mt)
#pragma unroll
        for (int nt = 0; nt < 4; ++nt) acc[mt][nt] = (f32x4)0.f;

#pragma unroll
    for (int s = 0; s < STEPS; ++s) {
        bf16x8 a[4];
#pragma unroll
        for (int mt = 0; mt < 4; ++mt)
            a[mt] = *(const bf16x8*)(xin + (size_t)j[mt] * CI + s * 32 + quad * 8);
        const unsigned short* bp = Wp + ((((size_t)k * STEPS + s) * 4) * 64 + lane) * 8;
#pragma unroll
        for (int nt = 0; nt < 4; ++nt) {
            bf16x8 b = *(const bf16x8*)(bp + (size_t)nt * 64 * 8);
#pragma unroll
            for (int mt = 0; mt < 4; ++mt)
                acc[mt][nt] = __builtin_amdgcn_mfma_f32_16x16x32_bf16(
                    a[mt], b, acc[mt][nt], 0, 0, 0);
        }
    }

#pragma unroll
    for (int mt = 0; mt < 4; ++mt) {
        int4 ii4 = *(const int4*)(pi + base + mt * 16 + quad * 4);
        const int ii[4] = {ii4.x, ii4.y, ii4.z, ii4.w};
#pragma unroll
        for (int r = 0; r < 4; ++r) {
#pragma unroll
            for (int nt = 0; nt < 4; ++nt) {
                const int n = nt * 16 + col;
                float v = acc[mt][nt][r];
                if (OUT_BF16) {
                    // pair adjacent channels across lane^1 for pk_add_bf16
                    float pv = __shfl_xor(v, 1);
                    if (!(col & 1)) {
                        unsigned int d = (unsigned int)f2b(v)
                                       | ((unsigned int)f2b(pv) << 16);
                        atomic_pk_bf16(outh + (size_t)ii[r] * 64 + n, d);
                    }
                } else {
                    unsafeAtomicAdd(outf + (size_t)ii[r] * 64 + n, v);
                }
            }
        }
    }
}

// ---- bn+relu on bf16 h (in place); zero pad row NV ------------------------
__global__ __launch_bounds__(256) void bn1_k(
    unsigned short* __restrict__ h,
    const float* __restrict__ s, const float* __restrict__ b)
{
    const size_t e = ((size_t)blockIdx.x * 256 + threadIdx.x) * 8;
    if (e >= (size_t)(NV + 1) * 64) return;
    unsigned short* p = h + e;
    if (e >= (size_t)NV * 64) {
        *(ulonglong2*)p = ulonglong2{0, 0};
        return;
    }
    const int c0 = (int)(e & 63);
    ushort4 u0 = *(ushort4*)p;
    ushort4 u1 = *(ushort4*)(p + 4);
    unsigned short v[8] = {u0.x, u0.y, u0.z, u0.w, u1.x, u1.y, u1.z, u1.w};
#pragma unroll
    for (int q = 0; q < 8; ++q)
        v[q] = f2b(fmaxf(fmaf(b2f(v[q]), s[c0 + q], b[c0 + q]), 0.f));
    *(ushort4*)p       = ushort4{v[0], v[1], v[2], v[3]};
    *(ushort4*)(p + 4) = ushort4{v[4], v[5], v[6], v[7]};
}

// ---- bn+relu on f32 down (in place) ---------------------------------------
__global__ __launch_bounds__(256) void bn2_k(
    float4* __restrict__ d, const float* __restrict__ s, const float* __restrict__ b)
{
    const int t = blockIdx.x * 256 + threadIdx.x;
    if (t >= NV * 16) return;
    const int c = (t & 15) * 4;
    float4 v = d[t];
    v.x = fmaxf(fmaf(v.x, s[c],     b[c]),     0.f);
    v.y = fmaxf(fmaf(v.y, s[c + 1], b[c + 1]), 0.f);
    v.z = fmaxf(fmaf(v.z, s[c + 2], b[c + 2]), 0.f);
    v.w = fmaxf(fmaf(v.w, s[c + 3], b[c + 3]), 0.f);
    d[t] = v;
}

// ---- pool: dense gather MFMA over 8 taps (round-3, verified) --------------
__global__ __launch_bounds__(256) void pool_mfma(
    const float* __restrict__ down, const float* __restrict__ zrow,
    const unsigned short* __restrict__ Wp, const int* __restrict__ ck,
    const float* __restrict__ bns, const float* __restrict__ bnb,
    float* __restrict__ pout)
{
    const int lane = threadIdx.x & 63;
    const int wave = threadIdx.x >> 6;
    const int col = lane & 15, quad = lane >> 4;
    const int wbase = (blockIdx.x * 4 + wave) * 64;

    f32x4 acc[4][4];
#pragma unroll
    for (int mt = 0; mt < 4; ++mt)
#pragma unroll
        for (int nt = 0; nt < 4; ++nt) acc[mt][nt] = (f32x4)0.f;

    for (int kk = 0; kk < 8; ++kk) {
        int j[4];
#pragma unroll
        for (int mt = 0; mt < 4; ++mt) {
            int row = wbase + mt * 16 + col;
            j[mt] = ck[(size_t)(row < ND ? row : ND - 1) * 8 + kk];
        }
#pragma unroll
        for (int s = 0; s < 2; ++s) {
            bf16x8 a[4];
#pragma unroll
            for (int mt = 0; mt < 4; ++mt) {
                const float* ap = (j[mt] == NV ? zrow : down + (size_t)j[mt] * 64)
                                  + s * 32 + quad * 8;
                float4 f0 = *(const float4*)ap;
                float4 f1 = *(const float4*)(ap + 4);
                bf16x8 av;
                av[0] = (short)f2b(f0.x); av[1] = (short)f2b(f0.y);
                av[2] = (short)f2b(f0.z); av[3] = (short)f2b(f0.w);
                av[4] = (short)f2b(f1.x); av[5] = (short)f2b(f1.y);
                av[6] = (short)f2b(f1.z); av[7] = (short)f2b(f1.w);
                a[mt] = av;
            }
            const unsigned short* bp = Wp + ((((size_t)kk * 2 + s) * 4) * 64 + lane) * 8;
#pragma unroll
            for (int nt = 0; nt < 4; ++nt) {
                bf16x8 b = *(const bf16x8*)(bp + (size_t)nt * 64 * 8);
#pragma unroll
                for (int mt = 0; mt < 4; ++mt)
                    acc[mt][nt] = __builtin_amdgcn_mfma_f32_16x16x32_bf16(
                        a[mt], b, acc[mt][nt], 0, 0, 0);
            }
        }
    }

#pragma unroll
    for (int nt = 0; nt < 4; ++nt) {
        const int n = nt * 16 + col;
        const float sc = bns[n], bi = bnb[n];
#pragma unroll
        for (int mt = 0; mt < 4; ++mt)
#pragma unroll
            for (int r = 0; r < 4; ++r) {
                int row = wbase + mt * 16 + quad * 4 + r;
                if (row < ND)
                    pout[(size_t)row * 64 + n] = fmaxf(fmaf(acc[mt][nt][r], sc, bi), 0.f);
            }
    }
}

extern "C" void kernel_launch(void* const* d_in, const int* in_sizes, int n_in,
                              void* d_out, int out_size, void* d_ws, size_t ws_size,
                              hipStream_t stream)
{
    const float* x    = (const float*)d_in[0];
    const float* W1   = (const float*)d_in[1];
    const float* bn1s = (const float*)d_in[2];
    const float* bn1b = (const float*)d_in[3];
    const float* W2   = (const float*)d_in[4];
    const float* bn2s = (const float*)d_in[5];
    const float* bn2b = (const float*)d_in[6];
    const float* Wp   = (const float*)d_in[7];
    const float* bnps = (const float*)d_in[8];
    const float* bnpb = (const float*)d_in[9];
    const int* km_in  = (const int*)d_in[10];
    const int* kp_in  = (const int*)d_in[12];
    const int* kp_out = (const int*)d_in[13];

    float* down = (float*)d_out;                     // [NV,64] output 0
    float* pout = (float*)d_out + (size_t)NV * 64;   // [ND,64] output 1
    // note: conv2 pad tiles atomic-add into down[NV] == pout[0..64) — pool
    // fully overwrites pout afterwards, so this is harmless.

    char* ws = (char*)d_ws;
    unsigned short* x_bf = (unsigned short*)ws; ws += (size_t)(NV + 1) * 32 * 2; // 25.6MB
    unsigned short* h    = (unsigned short*)ws; ws += (size_t)(NV + 1) * 64 * 2; // 51.2MB
    int* pj   = (int*)ws;            ws += (size_t)CAP * 4;                      // 9.6MB
    int* pi   = (int*)ws;            ws += (size_t)CAP * 4;                      // 9.6MB
    int* ck   = (int*)ws;            ws += (size_t)ND * 8 * 4;                   // 3.2MB
    unsigned short* W1p = (unsigned short*)ws; ws += (size_t)27 * 32 * 64 * 2;
    unsigned short* W2p = (unsigned short*)ws; ws += (size_t)27 * 64 * 64 * 2;
    unsigned short* Wpp = (unsigned short*)ws; ws += (size_t)8 * 64 * 64 * 2;
    int* tkm  = (int*)ws;            ws += (size_t)CAP_TILES * 4;
    int* cnt  = (int*)ws;            ws += 64 * 4;
    int* cnt2 = (int*)ws;            ws += 64 * 4;
    int* ntl  = (int*)ws;            ws += 64 * 4;
    float* zrow = (float*)ws;        ws += 64 * 4;

    hipMemsetAsync(h, 0, (size_t)(NV + 1) * 64 * 2, stream);     // conv1 acc base
    hipMemsetAsync(down, 0, (size_t)NV * 64 * 4, stream);        // conv2 acc base

    cvt_bf16_k<<<(NV * 32 / 4 + 255) / 256, 256, 0, stream>>>(x, x_bf, NV * 32);
    pack_w_k<<<(27 * 1 * 4 * 64 + 255) / 256, 256, 0, stream>>>(W1, W1p, 27, 32);
    pack_w_k<<<(27 * 2 * 4 * 64 + 255) / 256, 256, 0, stream>>>(W2, W2p, 27, 64);
    pack_w_k<<<(8  * 2 * 4 * 64 + 255) / 256, 256, 0, stream>>>(Wp, Wpp, 8, 64);

    ck_init_k<<<(ND * 8 + 255) / 256, 256, 0, stream>>>(
        ck, cnt, x_bf + (size_t)NV * 32, zrow);
    ck_scatter_k<<<(8 * NV + 255) / 256, 256, 0, stream>>>(kp_in, kp_out, ck);

    const dim3 pgrid((NV + 2047) / 2048, 27);
    pair_count_k<<<pgrid, 256, 0, stream>>>(km_in, cnt);
    pair_scan_k<<<1, 64, 0, stream>>>(cnt, cnt2, tkm, ntl, pj, pi);
    pair_fill_k<<<pgrid, 256, 0, stream>>>(km_in, cnt2, pj, pi);

    const int cgrid = CAP_TILES / 4;   // early-exit past ntl[0]
    conv_sp<32, true ><<<cgrid, 256, 0, stream>>>(x_bf, W1p, pj, pi, tkm, ntl, nullptr, h);
    bn1_k<<<(int)(((size_t)(NV + 1) * 64 / 8 + 255) / 256), 256, 0, stream>>>(h, bn1s, bn1b);
    conv_sp<64, false><<<cgrid, 256, 0, stream>>>(h, W2p, pj, pi, tkm, ntl, down, nullptr);
    bn2_k<<<(NV * 16 + 255) / 256, 256, 0, stream>>>((float4*)down, bn2s, bn2b);

    pool_mfma<<<(ND + 255) / 256, 256, 0, stream>>>(down, zrow, Wpp, ck, bnps, bnpb, pout);
}

// Round 5
// 1302.142 us; speedup vs baseline: 2.3694x; 2.3694x over previous
//
#include <hip/hip_runtime.h>

// DownSample — sparse scatter-form MFMA implicit GEMM, atomic-free compaction.
//
// Round-5 change: pair-list build is now deterministic 3-phase
// (count -> single-block scan -> fill), zero global atomics. Round 4's
// atomicAdd slot allocator serialized ~21k waves on 27 cache lines (1.5 ms).
//
// MFMA 16x16x32 bf16 layouts (verified round 3):
//   A[m=lane&15][k=(lane>>4)*8+j]   B[k=(lane>>4)*8+j][n=lane&15]
//   C/D: n=lane&15, m=(lane>>4)*4+reg

#define NV 400000
#define ND 100000
#define CAP 2400000            // pair capacity (expected ~1.79M)
#define CAP_TILES (CAP / 64)   // 37500
#define CH 196                 // 2048-row chunks: ceil(NV/2048)
#define WCH (CH * 4)           // 512-row wave-chunks per tap

typedef __attribute__((ext_vector_type(8))) short  bf16x8;
typedef __attribute__((ext_vector_type(4))) float  f32x4;

__device__ __forceinline__ unsigned short f2b(float f) {
    unsigned int u = __builtin_bit_cast(unsigned int, f);
    u += 0x7fffu + ((u >> 16) & 1u);
    return (unsigned short)(u >> 16);
}
__device__ __forceinline__ float b2f(unsigned short u) {
    unsigned int v = (unsigned int)u << 16;
    return __builtin_bit_cast(float, v);
}
__device__ __forceinline__ void atomic_pk_bf16(unsigned short* p, unsigned int d) {
    asm volatile("global_atomic_pk_add_bf16 %0, %1, off" :: "v"(p), "v"(d) : "memory");
}

// ---- x fp32 -> bf16 -------------------------------------------------------
__global__ __launch_bounds__(256) void cvt_bf16_k(
    const float* __restrict__ in, unsigned short* __restrict__ out, int n)
{
    int t = (blockIdx.x * 256 + threadIdx.x) * 4;
    if (t >= n) return;
    float4 f = *(const float4*)(in + t);
    ushort4 u;
    u.x = f2b(f.x); u.y = f2b(f.y); u.z = f2b(f.z); u.w = f2b(f.w);
    *(ushort4*)(out + t) = u;
}

// ---- pack W[nk][ci][64] -> per-lane B fragments ---------------------------
__global__ __launch_bounds__(256) void pack_w_k(
    const float* __restrict__ W, unsigned short* __restrict__ out, int nk, int ci)
{
    int t = blockIdx.x * 256 + threadIdx.x;
    int steps = ci >> 5;
    if (t >= nk * steps * 4 * 64) return;
    int lane = t & 63;
    int nt   = (t >> 6) & 3;
    int rest = t >> 8;
    int s    = rest % steps;
    int k    = rest / steps;
    int col = lane & 15, quad = lane >> 4;
    int co = nt * 16 + col;
    bf16x8 frag;
#pragma unroll
    for (int j = 0; j < 8; ++j) {
        int cidx = s * 32 + quad * 8 + j;
        frag[j] = (short)f2b(W[((size_t)k * ci + cidx) * 64 + co]);
    }
    *(bf16x8*)(out + (size_t)t * 8) = frag;
}

// ---- pool map inversion + small-buffer init -------------------------------
__global__ __launch_bounds__(256) void ck_init_k(
    int* __restrict__ ck, unsigned short* __restrict__ xrow,
    float* __restrict__ zrow)
{
    int t = blockIdx.x * 256 + threadIdx.x;
    if (t < ND * 8) ck[t] = NV;
    if (t < 32) { ((ulonglong2*)xrow)[t] = ulonglong2{0, 0}; }
    if (t < 64) zrow[t] = 0.f;
}
__global__ __launch_bounds__(256) void ck_scatter_k(
    const int* __restrict__ kp_in, const int* __restrict__ kp_out,
    int* __restrict__ ck)
{
    int t = blockIdx.x * 256 + threadIdx.x;
    if (t >= 8 * NV) return;
    int j = kp_in[t];
    if (j == NV) return;
    int k = t / NV;
    ck[kp_out[t] * 8 + k] = j;
}

// ---- phase 1: per-(tap, wave-chunk) valid counts — NO atomics -------------
__global__ __launch_bounds__(256) void pair_cnt_k(
    const int* __restrict__ km, int* __restrict__ bcnt)
{
    const int lane = threadIdx.x & 63;
    const int wave = threadIdx.x >> 6;
    const int k = blockIdx.y, c = blockIdx.x;
    const int* __restrict__ kmr = km + (size_t)k * NV;
    const int base = c * 2048 + wave * 512;
    int cnt = 0;
#pragma unroll
    for (int u = 0; u < 8; ++u) {
        int i = base + u * 64 + lane;
        bool valid = (i < NV) && (kmr[i < NV ? i : 0] != NV);
        cnt += __popcll(__ballot(valid));
    }
    if (lane == 0) bcnt[(k * CH + c) * 4 + wave] = cnt;
}

// ---- phase 2: single-block scan -> wave bases, tap bases, tkm, pads -------
__global__ __launch_bounds__(256) void pair_scan_k(
    const int* __restrict__ bcnt, int* __restrict__ wbase,
    int* __restrict__ tkm, int* __restrict__ ntl,
    int* __restrict__ pj, int* __restrict__ pi)
{
    __shared__ int tot[27], tb[28];
    const int tid = threadIdx.x;
    if (tid < 27) {
        int s = 0;
        for (int e = 0; e < WCH; ++e) s += bcnt[tid * WCH + e];
        tot[tid] = s;
    }
    __syncthreads();
    if (tid == 0) {
        int o = 0;
        for (int k = 0; k < 27; ++k) { tb[k] = o; o += (tot[k] + 63) & ~63; }
        tb[27] = o;
        ntl[0] = o >> 6;
    }
    __syncthreads();
    if (tid < 27) {
        int run = tb[tid];
        for (int e = 0; e < WCH; ++e) {
            wbase[tid * WCH + e] = run;
            run += bcnt[tid * WCH + e];
        }
        const int end = tb[tid] + ((tot[tid] + 63) & ~63);
        for (int s2 = run; s2 < end; ++s2) { pj[s2] = NV; pi[s2] = NV; }
    }
    __syncthreads();
    const int ntiles = tb[27] >> 6;
    for (int t = tid; t < ntiles; t += 256) {
        int p = t << 6, kk = 26;
        for (int q = 0; q < 26; ++q) if (p < tb[q + 1]) { kk = q; break; }
        tkm[t] = kk;
    }
}

// ---- phase 3: fill at deterministic slots — NO atomics --------------------
__global__ __launch_bounds__(256) void pair_fill_k(
    const int* __restrict__ km, const int* __restrict__ wbase,
    int* __restrict__ pj, int* __restrict__ pi)
{
    const int lane = threadIdx.x & 63;
    const int wave = threadIdx.x >> 6;
    const int k = blockIdx.y, c = blockIdx.x;
    const int* __restrict__ kmr = km + (size_t)k * NV;
    const int base = c * 2048 + wave * 512;
    int off = wbase[(k * CH + c) * 4 + wave];
#pragma unroll
    for (int u = 0; u < 8; ++u) {
        int i = base + u * 64 + lane;
        int j = (i < NV) ? kmr[i] : NV;
        bool valid = (i < NV) && (j != NV);
        unsigned long long m = __ballot(valid);
        if (valid) {
            int r = __popcll(m & ((1ull << lane) - 1ull));
            pj[off + r] = j;
            pi[off + r] = i;
        }
        off += __popcll(m);
    }
}

// ---- sparse conv: wave = 64-pair tile, scatter-atomic output --------------
template <int CI, bool OUT_BF16>
__global__ __launch_bounds__(256) void conv_sp(
    const unsigned short* __restrict__ xin,
    const unsigned short* __restrict__ Wp,
    const int* __restrict__ pj, const int* __restrict__ pi,
    const int* __restrict__ tkm, const int* __restrict__ ntl,
    float* __restrict__ outf, unsigned short* __restrict__ outh)
{
    constexpr int STEPS = CI / 32;
    const int lane = threadIdx.x & 63;
    const int wave = threadIdx.x >> 6;
    const int col = lane & 15, quad = lane >> 4;

    const int tile = blockIdx.x * 4 + wave;
    if (tile >= ntl[0]) return;
    const int k = __builtin_amdgcn_readfirstlane(tkm[tile]);
    const int base = tile << 6;

    int j[4];
#pragma unroll
    for (int mt = 0; mt < 4; ++mt) j[mt] = pj[base + mt * 16 + col];

    f32x4 acc[4][4];
#pragma unroll
    for (int mt = 0; mt < 4; ++mt)
#pragma unroll
        for (int nt = 0; nt < 4; ++nt) acc[mt][nt] = (f32x4)0.f;

#pragma unroll
    for (int s = 0; s < STEPS; ++s) {
        bf16x8 a[4];
#pragma unroll
        for (int mt = 0; mt < 4; ++mt)
            a[mt] = *(const bf16x8*)(xin + (size_t)j[mt] * CI + s * 32 + quad * 8);
        const unsigned short* bp = Wp + ((((size_t)k * STEPS + s) * 4) * 64 + lane) * 8;
#pragma unroll
        for (int nt = 0; nt < 4; ++nt) {
            bf16x8 b = *(const bf16x8*)(bp + (size_t)nt * 64 * 8);
#pragma unroll
            for (int mt = 0; mt < 4; ++mt)
                acc[mt][nt] = __builtin_amdgcn_mfma_f32_16x16x32_bf16(
                    a[mt], b, acc[mt][nt], 0, 0, 0);
        }
    }

#pragma unroll
    for (int mt = 0; mt < 4; ++mt) {
        int4 ii4 = *(const int4*)(pi + base + mt * 16 + quad * 4);
        const int ii[4] = {ii4.x, ii4.y, ii4.z, ii4.w};
#pragma unroll
        for (int r = 0; r < 4; ++r) {
#pragma unroll
            for (int nt = 0; nt < 4; ++nt) {
                const int n = nt * 16 + col;
                float v = acc[mt][nt][r];
                if (OUT_BF16) {
                    float pv = __shfl_xor(v, 1);
                    if (!(col & 1)) {
                        unsigned int d = (unsigned int)f2b(v)
                                       | ((unsigned int)f2b(pv) << 16);
                        atomic_pk_bf16(outh + (size_t)ii[r] * 64 + n, d);
                    }
                } else {
                    unsafeAtomicAdd(outf + (size_t)ii[r] * 64 + n, v);
                }
            }
        }
    }
}

// ---- bn+relu on bf16 h (in place); zero pad row NV ------------------------
__global__ __launch_bounds__(256) void bn1_k(
    unsigned short* __restrict__ h,
    const float* __restrict__ s, const float* __restrict__ b)
{
    const size_t e = ((size_t)blockIdx.x * 256 + threadIdx.x) * 8;
    if (e >= (size_t)(NV + 1) * 64) return;
    unsigned short* p = h + e;
    if (e >= (size_t)NV * 64) {
        *(ulonglong2*)p = ulonglong2{0, 0};
        return;
    }
    const int c0 = (int)(e & 63);
    ushort4 u0 = *(ushort4*)p;
    ushort4 u1 = *(ushort4*)(p + 4);
    unsigned short v[8] = {u0.x, u0.y, u0.z, u0.w, u1.x, u1.y, u1.z, u1.w};
#pragma unroll
    for (int q = 0; q < 8; ++q)
        v[q] = f2b(fmaxf(fmaf(b2f(v[q]), s[c0 + q], b[c0 + q]), 0.f));
    *(ushort4*)p       = ushort4{v[0], v[1], v[2], v[3]};
    *(ushort4*)(p + 4) = ushort4{v[4], v[5], v[6], v[7]};
}

// ---- bn+relu on f32 down (in place) ---------------------------------------
__global__ __launch_bounds__(256) void bn2_k(
    float4* __restrict__ d, const float* __restrict__ s, const float* __restrict__ b)
{
    const int t = blockIdx.x * 256 + threadIdx.x;
    if (t >= NV * 16) return;
    const int c = (t & 15) * 4;
    float4 v = d[t];
    v.x = fmaxf(fmaf(v.x, s[c],     b[c]),     0.f);
    v.y = fmaxf(fmaf(v.y, s[c + 1], b[c + 1]), 0.f);
    v.z = fmaxf(fmaf(v.z, s[c + 2], b[c + 2]), 0.f);
    v.w = fmaxf(fmaf(v.w, s[c + 3], b[c + 3]), 0.f);
    d[t] = v;
}

// ---- pool: dense gather MFMA over 8 taps ----------------------------------
__global__ __launch_bounds__(256) void pool_mfma(
    const float* __restrict__ down, const float* __restrict__ zrow,
    const unsigned short* __restrict__ Wp, const int* __restrict__ ck,
    const float* __restrict__ bns, const float* __restrict__ bnb,
    float* __restrict__ pout)
{
    const int lane = threadIdx.x & 63;
    const int wave = threadIdx.x >> 6;
    const int col = lane & 15, quad = lane >> 4;
    const int wbase0 = (blockIdx.x * 4 + wave) * 64;

    f32x4 acc[4][4];
#pragma unroll
    for (int mt = 0; mt < 4; ++mt)
#pragma unroll
        for (int nt = 0; nt < 4; ++nt) acc[mt][nt] = (f32x4)0.f;

    for (int kk = 0; kk < 8; ++kk) {
        int j[4];
#pragma unroll
        for (int mt = 0; mt < 4; ++mt) {
            int row = wbase0 + mt * 16 + col;
            j[mt] = ck[(size_t)(row < ND ? row : ND - 1) * 8 + kk];
        }
#pragma unroll
        for (int s = 0; s < 2; ++s) {
            bf16x8 a[4];
#pragma unroll
            for (int mt = 0; mt < 4; ++mt) {
                const float* ap = (j[mt] == NV ? zrow : down + (size_t)j[mt] * 64)
                                  + s * 32 + quad * 8;
                float4 f0 = *(const float4*)ap;
                float4 f1 = *(const float4*)(ap + 4);
                bf16x8 av;
                av[0] = (short)f2b(f0.x); av[1] = (short)f2b(f0.y);
                av[2] = (short)f2b(f0.z); av[3] = (short)f2b(f0.w);
                av[4] = (short)f2b(f1.x); av[5] = (short)f2b(f1.y);
                av[6] = (short)f2b(f1.z); av[7] = (short)f2b(f1.w);
                a[mt] = av;
            }
            const unsigned short* bp = Wp + ((((size_t)kk * 2 + s) * 4) * 64 + lane) * 8;
#pragma unroll
            for (int nt = 0; nt < 4; ++nt) {
                bf16x8 b = *(const bf16x8*)(bp + (size_t)nt * 64 * 8);
#pragma unroll
                for (int mt = 0; mt < 4; ++mt)
                    acc[mt][nt] = __builtin_amdgcn_mfma_f32_16x16x32_bf16(
                        a[mt], b, acc[mt][nt], 0, 0, 0);
            }
        }
    }

#pragma unroll
    for (int nt = 0; nt < 4; ++nt) {
        const int n = nt * 16 + col;
        const float sc = bns[n], bi = bnb[n];
#pragma unroll
        for (int mt = 0; mt < 4; ++mt)
#pragma unroll
            for (int r = 0; r < 4; ++r) {
                int row = wbase0 + mt * 16 + quad * 4 + r;
                if (row < ND)
                    pout[(size_t)row * 64 + n] = fmaxf(fmaf(acc[mt][nt][r], sc, bi), 0.f);
            }
    }
}

extern "C" void kernel_launch(void* const* d_in, const int* in_sizes, int n_in,
                              void* d_out, int out_size, void* d_ws, size_t ws_size,
                              hipStream_t stream)
{
    const float* x    = (const float*)d_in[0];
    const float* W1   = (const float*)d_in[1];
    const float* bn1s = (const float*)d_in[2];
    const float* bn1b = (const float*)d_in[3];
    const float* W2   = (const float*)d_in[4];
    const float* bn2s = (const float*)d_in[5];
    const float* bn2b = (const float*)d_in[6];
    const float* Wp   = (const float*)d_in[7];
    const float* bnps = (const float*)d_in[8];
    const float* bnpb = (const float*)d_in[9];
    const int* km_in  = (const int*)d_in[10];
    const int* kp_in  = (const int*)d_in[12];
    const int* kp_out = (const int*)d_in[13];

    float* down = (float*)d_out;                     // [NV,64] output 0
    float* pout = (float*)d_out + (size_t)NV * 64;   // [ND,64] output 1
    // conv2 pad tiles scatter into row NV == pout[0..64): overwritten by pool.

    char* ws = (char*)d_ws;
    unsigned short* x_bf = (unsigned short*)ws; ws += (size_t)(NV + 1) * 32 * 2;
    unsigned short* h    = (unsigned short*)ws; ws += (size_t)(NV + 1) * 64 * 2;
    int* pj   = (int*)ws;            ws += (size_t)CAP * 4;
    int* pi   = (int*)ws;            ws += (size_t)CAP * 4;
    int* ck   = (int*)ws;            ws += (size_t)ND * 8 * 4;
    unsigned short* W1p = (unsigned short*)ws; ws += (size_t)27 * 32 * 64 * 2;
    unsigned short* W2p = (unsigned short*)ws; ws += (size_t)27 * 64 * 64 * 2;
    unsigned short* Wpp = (unsigned short*)ws; ws += (size_t)8 * 64 * 64 * 2;
    int* tkm   = (int*)ws;           ws += (size_t)CAP_TILES * 4;
    int* bcnt  = (int*)ws;           ws += (size_t)27 * WCH * 4;
    int* wbase = (int*)ws;           ws += (size_t)27 * WCH * 4;
    int* ntl   = (int*)ws;           ws += 64 * 4;
    float* zrow = (float*)ws;        ws += 64 * 4;

    hipMemsetAsync(h, 0, (size_t)(NV + 1) * 64 * 2, stream);
    hipMemsetAsync(down, 0, (size_t)NV * 64 * 4, stream);

    cvt_bf16_k<<<(NV * 32 / 4 + 255) / 256, 256, 0, stream>>>(x, x_bf, NV * 32);
    pack_w_k<<<(27 * 1 * 4 * 64 + 255) / 256, 256, 0, stream>>>(W1, W1p, 27, 32);
    pack_w_k<<<(27 * 2 * 4 * 64 + 255) / 256, 256, 0, stream>>>(W2, W2p, 27, 64);
    pack_w_k<<<(8  * 2 * 4 * 64 + 255) / 256, 256, 0, stream>>>(Wp, Wpp, 8, 64);

    ck_init_k<<<(ND * 8 + 255) / 256, 256, 0, stream>>>(
        ck, x_bf + (size_t)NV * 32, zrow);
    ck_scatter_k<<<(8 * NV + 255) / 256, 256, 0, stream>>>(kp_in, kp_out, ck);

    const dim3 pgrid(CH, 27);
    pair_cnt_k <<<pgrid, 256, 0, stream>>>(km_in, bcnt);
    pair_scan_k<<<1, 256, 0, stream>>>(bcnt, wbase, tkm, ntl, pj, pi);
    pair_fill_k<<<pgrid, 256, 0, stream>>>(km_in, wbase, pj, pi);

    const int cgrid = CAP_TILES / 4;   // waves past ntl[0] exit early
    conv_sp<32, true ><<<cgrid, 256, 0, stream>>>(x_bf, W1p, pj, pi, tkm, ntl, nullptr, h);
    bn1_k<<<(int)(((size_t)(NV + 1) * 64 / 8 + 255) / 256), 256, 0, stream>>>(h, bn1s, bn1b);
    conv_sp<64, false><<<cgrid, 256, 0, stream>>>(h, W2p, pj, pi, tkm, ntl, down, nullptr);
    bn2_k<<<(NV * 16 + 255) / 256, 256, 0, stream>>>((float4*)down, bn2s, bn2b);

    pool_mfma<<<(ND + 255) / 256, 256, 0, stream>>>(down, zrow, Wpp, ck, bnps, bnpb, pout);
}